// Round 1
// baseline (489.305 us; speedup 1.0000x reference)
//
#include <hip/hip_runtime.h>
#include <hip/hip_bf16.h>

// Problem constants (derived from reference: N=50000, F=256, E=800000, H=4, P=65)
#define K_DIM 256          // F
#define COLS  520          // 2 * H * P
#define P_DIM 65           // F/H + 1
#define PH    68           // padded per-head length (multiple of 4)
#define KOFF  272          // H * PH — offset of k-part in stored row
#define PCOLS 544          // 2 * H * PH — stored row stride

// GEMM tiling
#define BM 128
#define BN 128
#define BKK 16

// Map stored (padded, q/k-separated) column p -> original W row c, or -1 for pad.
// Stored layout: [q_h0(0..67) q_h1 q_h2 q_h3 | k_h0 k_h1 k_h2 k_h3]
// Original: col c = h*130 + w, w<65 => q, w>=65 => k (w-65)
__device__ __forceinline__ int map_p_to_c(int p) {
  if (p >= PCOLS) return -1;
  int off = 0;
  if (p >= KOFF) { p -= KOFF; off = P_DIM; }
  int h = p / PH;
  int w = p - h * PH;
  return (w < P_DIM) ? (h * 130 + off + w) : -1;
}

__global__ void __launch_bounds__(256) zero_f(float* __restrict__ p, int n) {
  int i = blockIdx.x * 256 + threadIdx.x;
  if (i < n) p[i] = 0.f;
}

// qk[row][p] = sum_k x[row][k] * W[c(p)][k] + b[c(p)]   (0 for pad cols)
__global__ void __launch_bounds__(256) gemm_qk(
    const float* __restrict__ x, const float* __restrict__ W,
    const float* __restrict__ b, float* __restrict__ qk, int M)
{
  __shared__ float As[BKK][BM];   // 8 KB, A transposed: As[k][row]
  __shared__ float Bs[BKK][BN];   // 8 KB, Bs[k][col]
  const int row0 = blockIdx.x * BM;
  const int p0   = blockIdx.y * BN;
  const int tid  = threadIdx.x;
  const int tx   = tid & 15;   // 16 col-threads
  const int ty   = tid >> 4;   // 16 row-threads

  float acc[8][8];
  #pragma unroll
  for (int i = 0; i < 8; ++i)
    #pragma unroll
    for (int j = 0; j < 8; ++j) acc[i][j] = 0.f;

  for (int k0 = 0; k0 < K_DIM; k0 += BKK) {
    // Load A tile: 128 rows x 16 k = 512 float4, 2 per thread
    #pragma unroll
    for (int i = 0; i < 2; ++i) {
      int f  = tid * 2 + i;        // 0..511
      int r  = f >> 2;             // 0..127
      int kc = (f & 3) << 2;       // 0,4,8,12
      int row = row0 + r;
      float4 v = make_float4(0.f, 0.f, 0.f, 0.f);
      if (row < M) v = *(const float4*)(x + (size_t)row * K_DIM + k0 + kc);
      As[kc + 0][r] = v.x; As[kc + 1][r] = v.y;
      As[kc + 2][r] = v.z; As[kc + 3][r] = v.w;
    }
    // Load B tile: 128 cols x 16 k; pad/out-of-range cols -> zeros
    #pragma unroll
    for (int i = 0; i < 2; ++i) {
      int f  = tid * 2 + i;
      int cI = f >> 2;             // 0..127
      int kc = (f & 3) << 2;
      int c  = map_p_to_c(p0 + cI);
      float4 v = make_float4(0.f, 0.f, 0.f, 0.f);
      if (c >= 0) v = *(const float4*)(W + (size_t)c * K_DIM + k0 + kc);
      Bs[kc + 0][cI] = v.x; Bs[kc + 1][cI] = v.y;
      Bs[kc + 2][cI] = v.z; Bs[kc + 3][cI] = v.w;
    }
    __syncthreads();
    #pragma unroll
    for (int kk = 0; kk < BKK; ++kk) {
      float a[8], bb[8];
      #pragma unroll
      for (int i = 0; i < 8; ++i) a[i] = As[kk][ty * 8 + i];
      #pragma unroll
      for (int j = 0; j < 8; ++j) bb[j] = Bs[kk][tx * 8 + j];
      #pragma unroll
      for (int i = 0; i < 8; ++i)
        #pragma unroll
        for (int j = 0; j < 8; ++j) acc[i][j] = fmaf(a[i], bb[j], acc[i][j]);
    }
    __syncthreads();
  }

  #pragma unroll
  for (int i = 0; i < 8; ++i) {
    int row = row0 + ty * 8 + i;
    if (row >= M) continue;
    #pragma unroll
    for (int j = 0; j < 8; ++j) {
      int p = p0 + tx * 8 + j;
      if (p >= PCOLS) continue;
      int c = map_p_to_c(p);
      float v = (c >= 0) ? (acc[i][j] + b[c]) : 0.f;
      qk[(size_t)row * PCOLS + p] = v;
    }
  }
}

// One wave per edge. 16 lanes per head. scores -> exp -> store ex, atomicAdd denom.
__global__ void __launch_bounds__(256) edge_pass(
    const float* __restrict__ qk, const int* __restrict__ ei,
    float* __restrict__ exb, float* __restrict__ denom, int E)
{
  int gid  = blockIdx.x * 256 + threadIdx.x;
  int e    = gid >> 6;
  int lane = threadIdx.x & 63;
  if (e >= E) return;
  int src = ei[e];
  int dst = ei[E + e];
  int h = lane >> 4;   // head
  int l = lane & 15;   // lane within head
  const float* qr = qk + (size_t)src * PCOLS + h * PH;          // q part
  const float* kr = qk + (size_t)dst * PCOLS + KOFF + h * PH;   // k part
  float4 qa = *(const float4*)(qr + l * 4);
  float4 kb = *(const float4*)(kr + l * 4);
  float s = qa.x * kb.x + qa.y * kb.y + qa.z * kb.z + qa.w * kb.w;
  if (l == 0) s += qr[64] * kr[64];   // 65th element
  s += __shfl_xor(s, 1);
  s += __shfl_xor(s, 2);
  s += __shfl_xor(s, 4);
  s += __shfl_xor(s, 8);
  if (l == 0) {
    float ev = expf(s);   // no max-subtraction needed: |s| <~ 6, exp safe in fp32
    exb[(size_t)e * 4 + h] = ev;
    unsafeAtomicAdd(&denom[(size_t)src * 4 + h], ev);
  }
}

__global__ void __launch_bounds__(256) finalize_k(
    const float* __restrict__ exb, const float* __restrict__ denom,
    const int* __restrict__ ei, float* __restrict__ out, int E)
{
  int e = blockIdx.x * 256 + threadIdx.x;
  if (e >= E) return;
  int src = ei[e];
  float4 ev = *(const float4*)(exb + (size_t)e * 4);
  float4 dv = *(const float4*)(denom + (size_t)src * 4);
  out[e] = 0.25f * (ev.x / dv.x + ev.y / dv.y + ev.z / dv.z + ev.w / dv.w);
}

extern "C" void kernel_launch(void* const* d_in, const int* in_sizes, int n_in,
                              void* d_out, int out_size, void* d_ws, size_t ws_size,
                              hipStream_t stream)
{
  const float* x  = (const float*)d_in[0];
  const int*   ei = (const int*)d_in[1];
  const float* W  = (const float*)d_in[2];
  const float* b  = (const float*)d_in[3];

  const int F = in_sizes[2] / in_sizes[3];   // 256
  const int M = in_sizes[0] / F;             // 50000
  const int E = in_sizes[1] / 2;             // 800000

  // Workspace layout (fp32): qk[M*544] | ex[E*4] | denom[M*4]
  float* qk    = (float*)d_ws;
  float* exb   = qk + (size_t)M * PCOLS;
  float* denom = exb + (size_t)E * 4;

  int dn = M * 4;
  hipLaunchKernelGGL(zero_f, dim3((dn + 255) / 256), dim3(256), 0, stream, denom, dn);

  dim3 gg((M + BM - 1) / BM, (PCOLS + BN - 1) / BN);
  hipLaunchKernelGGL(gemm_qk, gg, dim3(256), 0, stream, x, W, b, qk, M);

  int eblocks = (E + 3) / 4;   // 4 waves (edges) per 256-thread block
  hipLaunchKernelGGL(edge_pass, dim3(eblocks), dim3(256), 0, stream, qk, ei, exb, denom, E);

  hipLaunchKernelGGL(finalize_k, dim3((E + 255) / 256), dim3(256), 0, stream,
                     exb, denom, ei, (float*)d_out, E);
}

// Round 2
// 336.581 us; speedup vs baseline: 1.4538x; 1.4538x over previous
//
#include <hip/hip_runtime.h>
#include <hip/hip_bf16.h>

// Problem constants: N=50000, F=256, E=800000, H=4, P=65
#define K_DIM 256          // F
#define P_DIM 65           // F/H + 1
#define PH    68           // padded per-head length (multiple of 4)
#define KOFF  272          // H*PH — offset of k-part in stored row
#define PCOLS 544          // 2*H*PH — stored qk row stride (bf16 elems)
#define NPAD  576          // GEMM column padding: 9 tiles of 64

// MFMA GEMM tiling
#define GBM 128
#define GBN 64
#define GBK 32             // bf16 elems per K-step (one 16x16x32 MFMA)

typedef unsigned short u16;
using short8 = __attribute__((ext_vector_type(8))) short;
using f32x4  = __attribute__((ext_vector_type(4))) float;

// stored column p -> original W row c, or -1 for pad
__device__ __forceinline__ int map_p_to_c(int p) {
  if (p >= PCOLS) return -1;
  int off = 0;
  if (p >= KOFF) { p -= KOFF; off = P_DIM; }
  int h = p / PH;
  int w = p - h * PH;
  return (w < P_DIM) ? (h * 130 + off + w) : -1;
}

__device__ __forceinline__ float b2f(u16 u) {
  union { unsigned i; float f; } x; x.i = ((unsigned)u) << 16; return x.f;
}
__device__ __forceinline__ u16 f2b(float f) {
  __hip_bfloat16 h = __float2bfloat16(f);
  return *(u16*)&h;
}

__global__ void __launch_bounds__(256) zero_f(float* __restrict__ p, int n) {
  int i = blockIdx.x * 256 + threadIdx.x;
  if (i < n) p[i] = 0.f;
}

// x (fp32, M x 256) -> xh + xl (bf16, Mpad x 256), rows >= M zeroed
__global__ void __launch_bounds__(256) split_x(
    const float* __restrict__ x, u16* __restrict__ xh, u16* __restrict__ xl,
    int M, int Mpad)
{
  int idx = blockIdx.x * 256 + threadIdx.x;      // one float4 per thread
  int total = Mpad * (K_DIM / 4);
  if (idx >= total) return;
  int row = idx / (K_DIM / 4);
  float4 v = make_float4(0.f, 0.f, 0.f, 0.f);
  if (row < M) v = *(const float4*)(x + (size_t)idx * 4);
  float vv[4] = {v.x, v.y, v.z, v.w};
  ushort4 hh, ll;
  u16* hp = (u16*)&hh; u16* lp = (u16*)&ll;
  #pragma unroll
  for (int j = 0; j < 4; ++j) {
    u16 hb = f2b(vv[j]);
    float hf = b2f(hb);
    hp[j] = hb;
    lp[j] = f2b(vv[j] - hf);
  }
  *(ushort4*)(xh + (size_t)idx * 4) = hh;
  *(ushort4*)(xl + (size_t)idx * 4) = ll;
}

// W (fp32, 520 x 256) -> wh + wl (bf16, NPAD x 256, permuted/padded cols), bias vec
__global__ void __launch_bounds__(256) split_w(
    const float* __restrict__ W, const float* __restrict__ b,
    u16* __restrict__ wh, u16* __restrict__ wl, float* __restrict__ bias)
{
  int idx = blockIdx.x * 256 + threadIdx.x;      // one float4 per thread
  int total = NPAD * (K_DIM / 4);
  if (idx >= total) return;
  int p  = idx / (K_DIM / 4);
  int kc = (idx % (K_DIM / 4)) * 4;
  int c  = map_p_to_c(p);
  float4 v = make_float4(0.f, 0.f, 0.f, 0.f);
  if (c >= 0) v = *(const float4*)(W + (size_t)c * K_DIM + kc);
  float vv[4] = {v.x, v.y, v.z, v.w};
  ushort4 hh, ll;
  u16* hp = (u16*)&hh; u16* lp = (u16*)&ll;
  #pragma unroll
  for (int j = 0; j < 4; ++j) {
    u16 hb = f2b(vv[j]);
    float hf = b2f(hb);
    hp[j] = hb;
    lp[j] = f2b(vv[j] - hf);
  }
  *(ushort4*)(wh + (size_t)idx * 4) = hh;
  *(ushort4*)(wl + (size_t)idx * 4) = ll;
  if (kc == 0) bias[p] = (c >= 0) ? b[c] : 0.f;
}

// qk = (xh+xl) @ (wh+wl)^T + bias, dropping lo*lo: 3 accumulation phases.
// Output bf16, row stride PCOLS=544.
__global__ void __launch_bounds__(256) gemm_mfma(
    const u16* __restrict__ xh, const u16* __restrict__ xl,
    const u16* __restrict__ wh, const u16* __restrict__ wl,
    const float* __restrict__ bias, u16* __restrict__ qkb, int M)
{
  __shared__ u16 As[GBM * GBK];   // 8 KB
  __shared__ u16 Bs[GBN * GBK];   // 4 KB
  const int tid  = threadIdx.x;
  const int wave = tid >> 6, lane = tid & 63;
  const int l15 = lane & 15, lhi = lane >> 4;
  const int row0 = blockIdx.x * GBM, p0 = blockIdx.y * GBN;
  const int wr = (wave >> 1) * 64, wc = (wave & 1) * 32;  // wave's sub-tile: 64x32

  f32x4 acc[4][2];
  #pragma unroll
  for (int m = 0; m < 4; ++m)
    #pragma unroll
    for (int n = 0; n < 2; ++n) acc[m][n] = (f32x4){0.f, 0.f, 0.f, 0.f};

  for (int phase = 0; phase < 3; ++phase) {
    const u16* Ap = (phase == 2) ? xl : xh;
    const u16* Bp = (phase == 1) ? wl : wh;
    for (int k0 = 0; k0 < K_DIM; k0 += GBK) {
      // Stage A tile: 128 rows x 32 bf16 = 512 x 16B chunks; chunk f -> row f>>2, kchunk f&3
      #pragma unroll
      for (int i = 0; i < 2; ++i) {
        int f = wave * 128 + i * 64 + lane;
        int r = f >> 2, c = f & 3;
        const u16* g = Ap + (size_t)(row0 + r) * K_DIM + k0 + c * 8;
        u16* ldsb = As + (size_t)(wave * 128 + i * 64) * 8;  // wave-uniform base
        __builtin_amdgcn_global_load_lds(
            (const __attribute__((address_space(1))) void*)g,
            (__attribute__((address_space(3))) void*)ldsb, 16, 0, 0);
      }
      // Stage B tile: 64 cols x 32 bf16 = 256 x 16B chunks
      {
        int cI = tid >> 2, c = tid & 3;
        const u16* g = Bp + (size_t)(p0 + cI) * K_DIM + k0 + c * 8;
        u16* ldsb = Bs + (size_t)(wave * 64) * 8;
        __builtin_amdgcn_global_load_lds(
            (const __attribute__((address_space(1))) void*)g,
            (__attribute__((address_space(3))) void*)ldsb, 16, 0, 0);
      }
      asm volatile("s_waitcnt vmcnt(0)" ::: "memory");
      __syncthreads();

      short8 af[4], bfr[2];
      #pragma unroll
      for (int m = 0; m < 4; ++m)
        af[m] = *(const short8*)(As + (size_t)(wr + m * 16 + l15) * GBK + lhi * 8);
      #pragma unroll
      for (int n = 0; n < 2; ++n)
        bfr[n] = *(const short8*)(Bs + (size_t)(wc + n * 16 + l15) * GBK + lhi * 8);
      #pragma unroll
      for (int m = 0; m < 4; ++m)
        #pragma unroll
        for (int n = 0; n < 2; ++n)
          acc[m][n] = __builtin_amdgcn_mfma_f32_16x16x32_bf16(af[m], bfr[n], acc[m][n], 0, 0, 0);
      __syncthreads();
    }
  }

  // Epilogue: D row = wr + m*16 + lhi*4 + r, col = wc + n*16 + l15
  #pragma unroll
  for (int m = 0; m < 4; ++m) {
    #pragma unroll
    for (int n = 0; n < 2; ++n) {
      int p = p0 + wc + n * 16 + l15;
      #pragma unroll
      for (int r = 0; r < 4; ++r) {
        int row = row0 + wr + m * 16 + lhi * 4 + r;
        if (row < M && p < PCOLS) {
          float v = acc[m][n][r] + bias[p];
          qkb[(size_t)row * PCOLS + p] = f2b(v);
        }
      }
    }
  }
}

// One wave per edge, 16 lanes per head; bf16 gathers.
__global__ void __launch_bounds__(256) edge_pass(
    const u16* __restrict__ qkb, const int* __restrict__ ei,
    float* __restrict__ exb, float* __restrict__ denom, int E)
{
  int gid  = blockIdx.x * 256 + threadIdx.x;
  int e    = gid >> 6;
  if (e >= E) return;
  int lane = threadIdx.x & 63;
  int src = ei[e];
  int dst = ei[E + e];
  int h = lane >> 4;
  int l = lane & 15;
  const u16* qr = qkb + (size_t)src * PCOLS + h * PH;
  const u16* kr = qkb + (size_t)dst * PCOLS + KOFF + h * PH;
  ushort4 qa = *(const ushort4*)(qr + l * 4);
  ushort4 kb = *(const ushort4*)(kr + l * 4);
  float s = b2f(qa.x) * b2f(kb.x) + b2f(qa.y) * b2f(kb.y)
          + b2f(qa.z) * b2f(kb.z) + b2f(qa.w) * b2f(kb.w);
  if (l == 0) s += b2f(qr[64]) * b2f(kr[64]);   // 65th element
  s += __shfl_xor(s, 1);
  s += __shfl_xor(s, 2);
  s += __shfl_xor(s, 4);
  s += __shfl_xor(s, 8);
  if (l == 0) {
    float ev = __expf(s);   // |s| <~ 6: exp safe in fp32, no max-subtraction needed
    exb[(size_t)e * 4 + h] = ev;
    unsafeAtomicAdd(&denom[(size_t)src * 4 + h], ev);
  }
}

__global__ void __launch_bounds__(256) finalize_k(
    const float* __restrict__ exb, const float* __restrict__ denom,
    const int* __restrict__ ei, float* __restrict__ out, int E)
{
  int e = blockIdx.x * 256 + threadIdx.x;
  if (e >= E) return;
  int src = ei[e];
  float4 ev = *(const float4*)(exb + (size_t)e * 4);
  float4 dv = *(const float4*)(denom + (size_t)src * 4);
  out[e] = 0.25f * (ev.x / dv.x + ev.y / dv.y + ev.z / dv.z + ev.w / dv.w);
}

extern "C" void kernel_launch(void* const* d_in, const int* in_sizes, int n_in,
                              void* d_out, int out_size, void* d_ws, size_t ws_size,
                              hipStream_t stream)
{
  const float* x  = (const float*)d_in[0];
  const int*   ei = (const int*)d_in[1];
  const float* W  = (const float*)d_in[2];
  const float* b  = (const float*)d_in[3];

  const int F = in_sizes[2] / in_sizes[3];   // 256
  const int M = in_sizes[0] / F;             // 50000
  const int E = in_sizes[1] / 2;             // 800000

  const int mblocks = (M + GBM - 1) / GBM;   // 391
  const int Mpad    = mblocks * GBM;         // 50048

  // Workspace layout: [xh|xl] bf16 Mpad*256 each | [wh|wl] bf16 NPAD*256 each |
  //                   qkb bf16 M*544 | bias f32 NPAD | exb f32 E*4 | denom f32 M*4
  u16* xh  = (u16*)d_ws;
  u16* xl  = xh + (size_t)Mpad * K_DIM;
  u16* wh  = xl + (size_t)Mpad * K_DIM;
  u16* wl  = wh + (size_t)NPAD * K_DIM;
  u16* qkb = wl + (size_t)NPAD * K_DIM;
  float* bias  = (float*)(qkb + (size_t)M * PCOLS);
  float* exb   = bias + NPAD;
  float* denom = exb + (size_t)E * 4;

  int xtot = Mpad * (K_DIM / 4);
  hipLaunchKernelGGL(split_x, dim3((xtot + 255) / 256), dim3(256), 0, stream,
                     x, xh, xl, M, Mpad);
  int wtot = NPAD * (K_DIM / 4);
  hipLaunchKernelGGL(split_w, dim3((wtot + 255) / 256), dim3(256), 0, stream,
                     W, b, wh, wl, bias);
  int dn = M * 4;
  hipLaunchKernelGGL(zero_f, dim3((dn + 255) / 256), dim3(256), 0, stream, denom, dn);

  dim3 gg(mblocks, NPAD / GBN);
  hipLaunchKernelGGL(gemm_mfma, gg, dim3(256), 0, stream, xh, xl, wh, wl, bias, qkb, M);

  int eblocks = (E + 3) / 4;   // 4 waves (edges) per 256-thread block
  hipLaunchKernelGGL(edge_pass, dim3(eblocks), dim3(256), 0, stream, qkb, ei, exb, denom, E);

  hipLaunchKernelGGL(finalize_k, dim3((E + 255) / 256), dim3(256), 0, stream,
                     exb, denom, ei, (float*)d_out, E);
}

// Round 3
// 249.960 us; speedup vs baseline: 1.9575x; 1.3465x over previous
//
#include <hip/hip_runtime.h>
#include <hip/hip_bf16.h>

// N=50000, F=256, E=800000, H=4, P=65
#define K_DIM 256
#define ROWQK 520          // bf16 per node row: [q 4x64 | k 4x64 | qt 4 | kt 4], 1040 B
#define NPAD  640          // GEMM col padding: 5 tiles of 128
#define GBM 128
#define GBN 128
#define GBK 32

typedef unsigned short u16;
using short8  = __attribute__((ext_vector_type(8))) short;
using ushort8 = __attribute__((ext_vector_type(8))) unsigned short;
using f32x4   = __attribute__((ext_vector_type(4))) float;

__device__ __forceinline__ float asf(unsigned u) {
  union { unsigned i; float f; } x; x.i = u; return x.f;
}
__device__ __forceinline__ u16 f2b(float f) {
  __hip_bfloat16 h = __float2bfloat16(f); return *(u16*)&h;
}

// stored column p -> original W row c, or -1 for pad
// layout: p<256: q head h=p>>6 elem w=p&63 (c=h*130+w); p<512: k (c=h*130+65+w);
//         512..515: qt[h] (c=h*130+64); 516..519: kt[h] (c=h*130+129)
__device__ __forceinline__ int map2(int p) {
  if (p < 256) return (p >> 6) * 130 + (p & 63);
  if (p < 512) { int q = p - 256; return (q >> 6) * 130 + 65 + (q & 63); }
  if (p < 516) return (p - 512) * 130 + 64;
  if (p < 520) return (p - 516) * 130 + 129;
  return -1;
}

__global__ void __launch_bounds__(256) zero_f(float* __restrict__ p, int n) {
  int i = blockIdx.x * 256 + threadIdx.x;
  if (i < n) p[i] = 0.f;
}

// x fp32 (M x 256) -> bf16 (Mpad x 256), rows >= M zeroed. One ushort8 chunk/thread.
__global__ void __launch_bounds__(256) convert_x(
    const float* __restrict__ x, u16* __restrict__ xb, int M, int Mpad)
{
  int idx = blockIdx.x * 256 + threadIdx.x;      // chunk of 8 elems
  int total = Mpad * (K_DIM / 8);
  if (idx >= total) return;
  int row = idx / (K_DIM / 8);
  ushort8 o;
  if (row < M) {
    const float* s = x + (size_t)idx * 8;
    float4 a = *(const float4*)s;
    float4 b = *(const float4*)(s + 4);
    o[0] = f2b(a.x); o[1] = f2b(a.y); o[2] = f2b(a.z); o[3] = f2b(a.w);
    o[4] = f2b(b.x); o[5] = f2b(b.y); o[6] = f2b(b.z); o[7] = f2b(b.w);
  } else {
    #pragma unroll
    for (int j = 0; j < 8; ++j) o[j] = 0;
  }
  *(ushort8*)(xb + (size_t)idx * 8) = o;
}

// W fp32 (520 x 256) -> wb bf16 (NPAD x 256, permuted cols) + bias f32 (NPAD)
__global__ void __launch_bounds__(256) convert_w(
    const float* __restrict__ W, const float* __restrict__ b,
    u16* __restrict__ wb, float* __restrict__ bias)
{
  int idx = blockIdx.x * 256 + threadIdx.x;
  int total = NPAD * (K_DIM / 8);
  if (idx >= total) return;
  int p  = idx / (K_DIM / 8);
  int kc = (idx % (K_DIM / 8)) * 8;
  int c  = map2(p);
  ushort8 o;
  if (c >= 0) {
    const float* s = W + (size_t)c * K_DIM + kc;
    float4 a = *(const float4*)s;
    float4 v = *(const float4*)(s + 4);
    o[0] = f2b(a.x); o[1] = f2b(a.y); o[2] = f2b(a.z); o[3] = f2b(a.w);
    o[4] = f2b(v.x); o[5] = f2b(v.y); o[6] = f2b(v.z); o[7] = f2b(v.w);
  } else {
    #pragma unroll
    for (int j = 0; j < 8; ++j) o[j] = 0;
  }
  *(ushort8*)(wb + (size_t)idx * 8) = o;
  if (kc == 0) bias[p] = (c >= 0) ? b[c] : 0.f;
}

// qk = xb @ wb^T + bias  (single-phase bf16 MFMA), output bf16 row stride ROWQK
__global__ void __launch_bounds__(256) gemm_mfma(
    const u16* __restrict__ xb, const u16* __restrict__ wb,
    const float* __restrict__ bias, u16* __restrict__ qkb, int M)
{
  __shared__ u16 As[GBM * GBK];   // 8 KB
  __shared__ u16 Bs[GBN * GBK];   // 8 KB
  const int tid  = threadIdx.x;
  const int wave = tid >> 6, lane = tid & 63;
  const int l15 = lane & 15, lhi = lane >> 4;
  const int row0 = blockIdx.x * GBM, p0 = blockIdx.y * GBN;
  const int wr = (wave >> 1) * 64, wc = (wave & 1) * 64;  // wave sub-tile 64x64

  f32x4 acc[4][4];
  #pragma unroll
  for (int m = 0; m < 4; ++m)
    #pragma unroll
    for (int n = 0; n < 4; ++n) acc[m][n] = (f32x4){0.f, 0.f, 0.f, 0.f};

  for (int k0 = 0; k0 < K_DIM; k0 += GBK) {
    // A: 128 rows x 32 bf16 = 512 16B-chunks; chunk f -> row f>>2, kchunk f&3
    #pragma unroll
    for (int i = 0; i < 2; ++i) {
      int f = wave * 128 + i * 64 + lane;
      int r = f >> 2, c = f & 3;
      const u16* g = xb + (size_t)(row0 + r) * K_DIM + k0 + c * 8;
      u16* ldsb = As + (size_t)(wave * 128 + i * 64) * 8;
      __builtin_amdgcn_global_load_lds(
          (const __attribute__((address_space(1))) void*)g,
          (__attribute__((address_space(3))) void*)ldsb, 16, 0, 0);
    }
    // B: 128 cols x 32 bf16
    #pragma unroll
    for (int i = 0; i < 2; ++i) {
      int f = wave * 128 + i * 64 + lane;
      int r = f >> 2, c = f & 3;
      const u16* g = wb + (size_t)(p0 + r) * K_DIM + k0 + c * 8;
      u16* ldsb = Bs + (size_t)(wave * 128 + i * 64) * 8;
      __builtin_amdgcn_global_load_lds(
          (const __attribute__((address_space(1))) void*)g,
          (__attribute__((address_space(3))) void*)ldsb, 16, 0, 0);
    }
    asm volatile("s_waitcnt vmcnt(0)" ::: "memory");
    __syncthreads();

    short8 af[4], bf[4];
    #pragma unroll
    for (int m = 0; m < 4; ++m)
      af[m] = *(const short8*)(As + (size_t)(wr + m * 16 + l15) * GBK + lhi * 8);
    #pragma unroll
    for (int n = 0; n < 4; ++n)
      bf[n] = *(const short8*)(Bs + (size_t)(wc + n * 16 + l15) * GBK + lhi * 8);
    #pragma unroll
    for (int m = 0; m < 4; ++m)
      #pragma unroll
      for (int n = 0; n < 4; ++n)
        acc[m][n] = __builtin_amdgcn_mfma_f32_16x16x32_bf16(af[m], bf[n], acc[m][n], 0, 0, 0);
    __syncthreads();
  }

  // D row = wr + m*16 + lhi*4 + r, col = wc + n*16 + l15
  #pragma unroll
  for (int n = 0; n < 4; ++n) {
    int p = p0 + wc + n * 16 + l15;
    if (p >= ROWQK) continue;
    float bv = bias[p];
    #pragma unroll
    for (int m = 0; m < 4; ++m) {
      #pragma unroll
      for (int r = 0; r < 4; ++r) {
        int row = row0 + wr + m * 16 + lhi * 4 + r;
        if (row < M) qkb[(size_t)row * ROWQK + p] = f2b(acc[m][n][r] + bv);
      }
    }
  }
}

// One wave per edge. Lanes 0-31: q[src] main (16 B each), lanes 32-63: k[dst] main.
// One extra 8-B wave-load for tails. shfl_xor(32) aligns k under q.
__global__ void __launch_bounds__(256) edge_pass(
    const u16* __restrict__ qkb, const int* __restrict__ ei,
    float* __restrict__ exb, float* __restrict__ denom, int E)
{
  int gid = blockIdx.x * 256 + threadIdx.x;
  int e = gid >> 6;
  if (e >= E) return;
  int lane = threadIdx.x & 63;
  int src = ei[e];
  int dst = ei[E + e];

  int isK = lane >> 5;
  int sub = lane & 31;
  int node = isK ? dst : src;
  const u16* base = qkb + (size_t)node * ROWQK + isK * 256 + sub * 8;
  int4 mi = *(const int4*)base;                 // 8 bf16 main payload

  const u16* tbase = qkb + ((lane & 1) ? ((size_t)dst * ROWQK + 516)
                                       : ((size_t)src * ROWQK + 512));
  int2 ti = *(const int2*)tbase;                // 4 bf16 tail payload

  // bring k data to q lanes
  int4 ki;
  ki.x = __shfl_xor(mi.x, 32); ki.y = __shfl_xor(mi.y, 32);
  ki.z = __shfl_xor(mi.z, 32); ki.w = __shfl_xor(mi.w, 32);

  const unsigned* qu = (const unsigned*)&mi;
  const unsigned* ku = (const unsigned*)&ki;
  float s = 0.f;
  #pragma unroll
  for (int j = 0; j < 4; ++j) {
    s = fmaf(asf(qu[j] << 16), asf(ku[j] << 16), s);
    s = fmaf(asf(qu[j] & 0xffff0000u), asf(ku[j] & 0xffff0000u), s);
  }
  // reduce across the 8 lanes of this head
  s += __shfl_xor(s, 1);
  s += __shfl_xor(s, 2);
  s += __shfl_xor(s, 4);

  // tails: qt from lane 0, kt from lane 1; pick this head's element
  int h = (lane >> 3) & 3;
  unsigned qtx = __shfl(ti.x, 0), qty = __shfl(ti.y, 0);
  unsigned ktx = __shfl(ti.x, 1), kty = __shfl(ti.y, 1);
  unsigned qtw = (h & 2) ? qty : qtx;
  unsigned ktw = (h & 2) ? kty : ktx;
  unsigned qsel = (h & 1) ? (qtw & 0xffff0000u) : (qtw << 16);
  unsigned ksel = (h & 1) ? (ktw & 0xffff0000u) : (ktw << 16);
  s = fmaf(asf(qsel), asf(ksel), s);

  if (lane < 32 && (lane & 7) == 0) {
    float ev = __expf(s);   // |s| <~ 6: fp32-safe, no max-subtraction needed
    exb[(size_t)e * 4 + h] = ev;
    unsafeAtomicAdd(&denom[(size_t)src * 4 + h], ev);
  }
}

__global__ void __launch_bounds__(256) finalize_k(
    const float* __restrict__ exb, const float* __restrict__ denom,
    const int* __restrict__ ei, float* __restrict__ out, int E)
{
  int e = blockIdx.x * 256 + threadIdx.x;
  if (e >= E) return;
  int src = ei[e];
  float4 ev = *(const float4*)(exb + (size_t)e * 4);
  float4 dv = *(const float4*)(denom + (size_t)src * 4);
  out[e] = 0.25f * (ev.x / dv.x + ev.y / dv.y + ev.z / dv.z + ev.w / dv.w);
}

extern "C" void kernel_launch(void* const* d_in, const int* in_sizes, int n_in,
                              void* d_out, int out_size, void* d_ws, size_t ws_size,
                              hipStream_t stream)
{
  const float* x  = (const float*)d_in[0];
  const int*   ei = (const int*)d_in[1];
  const float* W  = (const float*)d_in[2];
  const float* b  = (const float*)d_in[3];

  const int F = in_sizes[2] / in_sizes[3];   // 256
  const int M = in_sizes[0] / F;             // 50000
  const int E = in_sizes[1] / 2;             // 800000

  const int mblocks = (M + GBM - 1) / GBM;   // 391
  const int Mpad    = mblocks * GBM;         // 50048

  // ws: xb bf16 Mpad*256 | wb bf16 NPAD*256 | qkb bf16 M*520 | bias f32 NPAD |
  //     exb f32 E*4 | denom f32 M*4
  u16* xb  = (u16*)d_ws;
  u16* wb  = xb + (size_t)Mpad * K_DIM;
  u16* qkb = wb + (size_t)NPAD * K_DIM;
  float* bias  = (float*)(qkb + (size_t)M * ROWQK);
  float* exb   = bias + NPAD;
  float* denom = exb + (size_t)E * 4;

  int xtot = Mpad * (K_DIM / 8);
  hipLaunchKernelGGL(convert_x, dim3((xtot + 255) / 256), dim3(256), 0, stream,
                     x, xb, M, Mpad);
  int wtot = NPAD * (K_DIM / 8);
  hipLaunchKernelGGL(convert_w, dim3((wtot + 255) / 256), dim3(256), 0, stream,
                     W, b, wb, bias);
  int dn = M * 4;
  hipLaunchKernelGGL(zero_f, dim3((dn + 255) / 256), dim3(256), 0, stream, denom, dn);

  dim3 gg(mblocks, NPAD / GBN);
  hipLaunchKernelGGL(gemm_mfma, gg, dim3(256), 0, stream, xb, wb, bias, qkb, M);

  int eblocks = (E + 3) / 4;   // 4 edges (waves) per 256-thread block
  hipLaunchKernelGGL(edge_pass, dim3(eblocks), dim3(256), 0, stream,
                     qkb, ei, exb, denom, E);

  hipLaunchKernelGGL(finalize_k, dim3((E + 255) / 256), dim3(256), 0, stream,
                     exb, denom, ei, (float*)d_out, E);
}

// Round 4
// 221.593 us; speedup vs baseline: 2.2081x; 1.1280x over previous
//
#include <hip/hip_runtime.h>
#include <hip/hip_bf16.h>

// N=50000, F=256, E=800000, H=4, P=65
#define K_DIM 256
#define ROWQK 520          // useful bf16 per node row: [q 4x64 | k 4x64 | qt 4 | kt 4]
#define RSTRIDE 544        // stored row stride in bf16 elems (1088 B, 64-B aligned)
#define NPAD  640          // GEMM col padding: 5 tiles of 128
#define GBM 128
#define GBN 128
#define GBK 32

typedef unsigned short u16;
using short8  = __attribute__((ext_vector_type(8))) short;
using ushort8 = __attribute__((ext_vector_type(8))) unsigned short;
using f32x4   = __attribute__((ext_vector_type(4))) float;
using f32x2   = __attribute__((ext_vector_type(2))) float;

__device__ __forceinline__ float asf(unsigned u) {
  union { unsigned i; float f; } x; x.i = u; return x.f;
}
__device__ __forceinline__ u16 f2b(float f) {
  __hip_bfloat16 h = __float2bfloat16(f); return *(u16*)&h;
}

// stored column p -> original W row c, or -1 for pad
// p<256: q head h=p>>6 elem w=p&63 (c=h*130+w); p<512: k (c=h*130+65+w);
// 512..515: qt[h] (c=h*130+64); 516..519: kt[h] (c=h*130+129)
__device__ __forceinline__ int map2(int p) {
  if (p < 256) return (p >> 6) * 130 + (p & 63);
  if (p < 512) { int q = p - 256; return (q >> 6) * 130 + 65 + (q & 63); }
  if (p < 516) return (p - 512) * 130 + 64;
  if (p < 520) return (p - 516) * 130 + 129;
  return -1;
}

__global__ void __launch_bounds__(256) zero_f(float* __restrict__ p, int n) {
  int i = blockIdx.x * 256 + threadIdx.x;
  if (i < n) p[i] = 0.f;
}

// x fp32 (M x 256) -> bf16 (Mpad x 256), rows >= M zeroed
__global__ void __launch_bounds__(256) convert_x(
    const float* __restrict__ x, u16* __restrict__ xb, int M, int Mpad)
{
  int idx = blockIdx.x * 256 + threadIdx.x;
  int total = Mpad * (K_DIM / 8);
  if (idx >= total) return;
  int row = idx / (K_DIM / 8);
  ushort8 o;
  if (row < M) {
    const float* s = x + (size_t)idx * 8;
    float4 a = *(const float4*)s;
    float4 b = *(const float4*)(s + 4);
    o[0] = f2b(a.x); o[1] = f2b(a.y); o[2] = f2b(a.z); o[3] = f2b(a.w);
    o[4] = f2b(b.x); o[5] = f2b(b.y); o[6] = f2b(b.z); o[7] = f2b(b.w);
  } else {
    #pragma unroll
    for (int j = 0; j < 8; ++j) o[j] = 0;
  }
  *(ushort8*)(xb + (size_t)idx * 8) = o;
}

// W fp32 (520 x 256) -> wb bf16 (NPAD x 256, permuted cols) + bias f32 (NPAD)
__global__ void __launch_bounds__(256) convert_w(
    const float* __restrict__ W, const float* __restrict__ b,
    u16* __restrict__ wb, float* __restrict__ bias)
{
  int idx = blockIdx.x * 256 + threadIdx.x;
  int total = NPAD * (K_DIM / 8);
  if (idx >= total) return;
  int p  = idx / (K_DIM / 8);
  int kc = (idx % (K_DIM / 8)) * 8;
  int c  = map2(p);
  ushort8 o;
  if (c >= 0) {
    const float* s = W + (size_t)c * K_DIM + kc;
    float4 a = *(const float4*)s;
    float4 v = *(const float4*)(s + 4);
    o[0] = f2b(a.x); o[1] = f2b(a.y); o[2] = f2b(a.z); o[3] = f2b(a.w);
    o[4] = f2b(v.x); o[5] = f2b(v.y); o[6] = f2b(v.z); o[7] = f2b(v.w);
  } else {
    #pragma unroll
    for (int j = 0; j < 8; ++j) o[j] = 0;
  }
  *(ushort8*)(wb + (size_t)idx * 8) = o;
  if (kc == 0) bias[p] = (c >= 0) ? b[c] : 0.f;
}

// qk = xb @ wb^T + bias (bf16 MFMA), output bf16 row stride RSTRIDE
__global__ void __launch_bounds__(256) gemm_mfma(
    const u16* __restrict__ xb, const u16* __restrict__ wb,
    const float* __restrict__ bias, u16* __restrict__ qkb, int M)
{
  __shared__ u16 As[GBM * GBK];
  __shared__ u16 Bs[GBN * GBK];
  const int tid  = threadIdx.x;
  const int wave = tid >> 6, lane = tid & 63;
  const int l15 = lane & 15, lhi = lane >> 4;
  const int row0 = blockIdx.x * GBM, p0 = blockIdx.y * GBN;
  const int wr = (wave >> 1) * 64, wc = (wave & 1) * 64;

  f32x4 acc[4][4];
  #pragma unroll
  for (int m = 0; m < 4; ++m)
    #pragma unroll
    for (int n = 0; n < 4; ++n) acc[m][n] = (f32x4){0.f, 0.f, 0.f, 0.f};

  for (int k0 = 0; k0 < K_DIM; k0 += GBK) {
    #pragma unroll
    for (int i = 0; i < 2; ++i) {
      int f = wave * 128 + i * 64 + lane;
      int r = f >> 2, c = f & 3;
      const u16* g = xb + (size_t)(row0 + r) * K_DIM + k0 + c * 8;
      u16* ldsb = As + (size_t)(wave * 128 + i * 64) * 8;
      __builtin_amdgcn_global_load_lds(
          (const __attribute__((address_space(1))) void*)g,
          (__attribute__((address_space(3))) void*)ldsb, 16, 0, 0);
    }
    #pragma unroll
    for (int i = 0; i < 2; ++i) {
      int f = wave * 128 + i * 64 + lane;
      int r = f >> 2, c = f & 3;
      const u16* g = wb + (size_t)(p0 + r) * K_DIM + k0 + c * 8;
      u16* ldsb = Bs + (size_t)(wave * 128 + i * 64) * 8;
      __builtin_amdgcn_global_load_lds(
          (const __attribute__((address_space(1))) void*)g,
          (__attribute__((address_space(3))) void*)ldsb, 16, 0, 0);
    }
    asm volatile("s_waitcnt vmcnt(0)" ::: "memory");
    __syncthreads();

    short8 af[4], bf[4];
    #pragma unroll
    for (int m = 0; m < 4; ++m)
      af[m] = *(const short8*)(As + (size_t)(wr + m * 16 + l15) * GBK + lhi * 8);
    #pragma unroll
    for (int n = 0; n < 4; ++n)
      bf[n] = *(const short8*)(Bs + (size_t)(wc + n * 16 + l15) * GBK + lhi * 8);
    #pragma unroll
    for (int m = 0; m < 4; ++m)
      #pragma unroll
      for (int n = 0; n < 4; ++n)
        acc[m][n] = __builtin_amdgcn_mfma_f32_16x16x32_bf16(af[m], bf[n], acc[m][n], 0, 0, 0);
    __syncthreads();
  }

  #pragma unroll
  for (int n = 0; n < 4; ++n) {
    int p = p0 + wc + n * 16 + l15;
    if (p >= ROWQK) continue;
    float bv = bias[p];
    #pragma unroll
    for (int m = 0; m < 4; ++m) {
      #pragma unroll
      for (int r = 0; r < 4; ++r) {
        int row = row0 + wr + m * 16 + lhi * 4 + r;
        if (row < M) qkb[(size_t)row * RSTRIDE + p] = f2b(acc[m][n][r] + bv);
      }
    }
  }
}

// 8 edges per wave, 8 lanes per edge. Lane l of edge g loads 64 B of q[src]
// AND 64 B of k[dst] (no swap shuffles needed). Head h = lanes {2h, 2h+1}.
__global__ void __launch_bounds__(256) edge_pass(
    const u16* __restrict__ qkb, const int* __restrict__ ei,
    float* __restrict__ exb, float* __restrict__ denom, int E)
{
  const int tid  = threadIdx.x;
  const int wave = tid >> 6, lane = tid & 63;
  const int g = lane >> 3;          // edge slot in wave
  const int l = lane & 7;           // lane within edge
  const int eBase = (blockIdx.x * 4 + wave) * 8;
  const int e = eBase + g;
  const bool valid = e < E;
  const int ec = valid ? e : 0;
  const int src = ei[ec];
  const int dst = ei[E + ec];

  const u16* qrow = qkb + (size_t)(unsigned)(src * RSTRIDE) + l * 32;
  const u16* krow = qkb + (size_t)(unsigned)(dst * RSTRIDE) + 256 + l * 32;

  // tail payload: lane l==0 loads src tails (qt x4), l==1 loads dst tails (kt x4)
  int2 ti = make_int2(0, 0);
  if (l < 2) {
    const u16* tp = qkb + (size_t)(unsigned)((l ? dst : src) * RSTRIDE) + (l ? 516 : 512);
    ti = *(const int2*)tp;
  }

  f32x2 a2 = {0.f, 0.f};
  #pragma unroll
  for (int c = 0; c < 4; ++c) {
    uint4 qv = *(const uint4*)(qrow + c * 8);
    uint4 kv = *(const uint4*)(krow + c * 8);
    const unsigned* qd = (const unsigned*)&qv;
    const unsigned* kd = (const unsigned*)&kv;
    #pragma unroll
    for (int j = 0; j < 4; ++j) {
      f32x2 qa = { asf(qd[j] << 16), asf(qd[j] & 0xffff0000u) };
      f32x2 ka = { asf(kd[j] << 16), asf(kd[j] & 0xffff0000u) };
      a2 += qa * ka;
    }
  }
  float s = a2[0] + a2[1];
  s += __shfl_xor(s, 1);            // head sum (lanes 2h, 2h+1)

  // tail: even lane fetches qt pair-dwords from lane 8g, odd lane kt from 8g+1
  const int h = l >> 1;
  int idxA = ((g << 3) | (l & 1)) << 2;
  int w01 = __builtin_amdgcn_ds_bpermute(idxA, ti.x);
  int w23 = __builtin_amdgcn_ds_bpermute(idxA, ti.y);
  unsigned wsel = (h & 2) ? (unsigned)w23 : (unsigned)w01;
  float tv = (h & 1) ? asf(wsel & 0xffff0000u) : asf(wsel << 16);
  float to = __shfl_xor(tv, 1);     // even lane: kt[h]; odd lane: qt[h]
  s = fmaf(tv, to, s);              // both lanes add the same product once

  float ev = __expf(s);             // |s| <~ 8: fp32-safe, no max-subtraction
  if (valid && (l & 1) == 0) {
    exb[(size_t)e * 4 + h] = ev;    // even lanes: contiguous 32 floats per wave
    unsafeAtomicAdd(&denom[(size_t)src * 4 + h], ev);
  }
}

__global__ void __launch_bounds__(256) finalize_k(
    const float* __restrict__ exb, const float* __restrict__ denom,
    const int* __restrict__ ei, float* __restrict__ out, int E)
{
  int e = blockIdx.x * 256 + threadIdx.x;
  if (e >= E) return;
  int src = ei[e];
  float4 ev = *(const float4*)(exb + (size_t)e * 4);
  float4 dv = *(const float4*)(denom + (size_t)src * 4);
  out[e] = 0.25f * (ev.x / dv.x + ev.y / dv.y + ev.z / dv.z + ev.w / dv.w);
}

extern "C" void kernel_launch(void* const* d_in, const int* in_sizes, int n_in,
                              void* d_out, int out_size, void* d_ws, size_t ws_size,
                              hipStream_t stream)
{
  const float* x  = (const float*)d_in[0];
  const int*   ei = (const int*)d_in[1];
  const float* W  = (const float*)d_in[2];
  const float* b  = (const float*)d_in[3];

  const int F = in_sizes[2] / in_sizes[3];   // 256
  const int M = in_sizes[0] / F;             // 50000
  const int E = in_sizes[1] / 2;             // 800000

  const int mblocks = (M + GBM - 1) / GBM;
  const int Mpad    = mblocks * GBM;

  // ws: xb bf16 Mpad*256 | wb bf16 NPAD*256 | qkb bf16 M*RSTRIDE | bias f32 NPAD |
  //     exb f32 E*4 | denom f32 M*4
  u16* xb  = (u16*)d_ws;
  u16* wb  = xb + (size_t)Mpad * K_DIM;
  u16* qkb = wb + (size_t)NPAD * K_DIM;
  float* bias  = (float*)(qkb + (size_t)M * RSTRIDE);
  float* exb   = bias + NPAD;
  float* denom = exb + (size_t)E * 4;

  int xtot = Mpad * (K_DIM / 8);
  hipLaunchKernelGGL(convert_x, dim3((xtot + 255) / 256), dim3(256), 0, stream,
                     x, xb, M, Mpad);
  int wtot = NPAD * (K_DIM / 8);
  hipLaunchKernelGGL(convert_w, dim3((wtot + 255) / 256), dim3(256), 0, stream,
                     W, b, wb, bias);
  int dn = M * 4;
  hipLaunchKernelGGL(zero_f, dim3((dn + 255) / 256), dim3(256), 0, stream, denom, dn);

  dim3 gg(mblocks, NPAD / GBN);
  hipLaunchKernelGGL(gemm_mfma, gg, dim3(256), 0, stream, xb, wb, bias, qkb, M);

  int eblocks = (E + 31) / 32;   // 32 edges per 256-thread block (8 per wave)
  hipLaunchKernelGGL(edge_pass, dim3(eblocks), dim3(256), 0, stream,
                     qkb, ei, exb, denom, E);

  hipLaunchKernelGGL(finalize_k, dim3((E + 255) / 256), dim3(256), 0, stream,
                     exb, denom, ei, (float*)d_out, E);
}

// Round 5
// 180.932 us; speedup vs baseline: 2.7044x; 1.2247x over previous
//
#include <hip/hip_runtime.h>
#include <hip/hip_bf16.h>

// N=50000, F=256, E=800000, H=4, P=65
#define K_DIM 256
#define RQ    512          // qkb row stride in bf16 elems (1024 B): [q 4x64 | k 4x64]
#define NPAD  640          // GEMM col padding: 5 tiles of 128
#define GBM 128
#define GBN 128
#define GBK 32
#define EPITCH 152         // epilogue LDS pitch (elems): 304 B, 16B-multiple, bank-skewed

typedef unsigned short u16;
using short8  = __attribute__((ext_vector_type(8))) short;
using ushort8 = __attribute__((ext_vector_type(8))) unsigned short;
using f32x4   = __attribute__((ext_vector_type(4))) float;
using f32x2   = __attribute__((ext_vector_type(2))) float;

__device__ __forceinline__ float asf(unsigned u) {
  union { unsigned i; float f; } x; x.i = u; return x.f;
}
__device__ __forceinline__ u16 f2b(float f) {
  __hip_bfloat16 h = __float2bfloat16(f); return *(u16*)&h;
}

// stored column p -> original W row c, or -1 for pad
// p<256: q head h=p>>6 elem w=p&63 (c=h*130+w); p<512: k (c=h*130+65+w);
// 512..515: qt[h] (c=h*130+64); 516..519: kt[h] (c=h*130+129)
__device__ __forceinline__ int map2(int p) {
  if (p < 256) return (p >> 6) * 130 + (p & 63);
  if (p < 512) { int q = p - 256; return (q >> 6) * 130 + 65 + (q & 63); }
  if (p < 516) return (p - 512) * 130 + 64;
  if (p < 520) return (p - 516) * 130 + 129;
  return -1;
}

// Fused: convert_x | convert_w(+bias) | zero denom
__global__ void __launch_bounds__(256) prep(
    const float* __restrict__ x, const float* __restrict__ W,
    const float* __restrict__ bv,
    u16* __restrict__ xb, u16* __restrict__ wb,
    float* __restrict__ bias, float* __restrict__ denom,
    int M, int Mpad, int xblocks, int wblocks, int dn)
{
  const int blk = blockIdx.x, tid = threadIdx.x;
  if (blk < xblocks) {
    int idx = blk * 256 + tid;                 // chunk of 8 elems
    int total = Mpad * (K_DIM / 8);
    if (idx >= total) return;
    int row = idx / (K_DIM / 8);
    ushort8 o;
    if (row < M) {
      const float* s = x + (size_t)idx * 8;
      float4 a = *(const float4*)s;
      float4 b = *(const float4*)(s + 4);
      o[0] = f2b(a.x); o[1] = f2b(a.y); o[2] = f2b(a.z); o[3] = f2b(a.w);
      o[4] = f2b(b.x); o[5] = f2b(b.y); o[6] = f2b(b.z); o[7] = f2b(b.w);
    } else {
      #pragma unroll
      for (int j = 0; j < 8; ++j) o[j] = 0;
    }
    *(ushort8*)(xb + (size_t)idx * 8) = o;
  } else if (blk < xblocks + wblocks) {
    int idx = (blk - xblocks) * 256 + tid;
    int total = NPAD * (K_DIM / 8);
    if (idx >= total) return;
    int p  = idx / (K_DIM / 8);
    int kc = (idx % (K_DIM / 8)) * 8;
    int c  = map2(p);
    ushort8 o;
    if (c >= 0) {
      const float* s = W + (size_t)c * K_DIM + kc;
      float4 a = *(const float4*)s;
      float4 v = *(const float4*)(s + 4);
      o[0] = f2b(a.x); o[1] = f2b(a.y); o[2] = f2b(a.z); o[3] = f2b(a.w);
      o[4] = f2b(v.x); o[5] = f2b(v.y); o[6] = f2b(v.z); o[7] = f2b(v.w);
    } else {
      #pragma unroll
      for (int j = 0; j < 8; ++j) o[j] = 0;
    }
    *(ushort8*)(wb + (size_t)idx * 8) = o;
    if (kc == 0) bias[p] = (c >= 0) ? bv[c] : 0.f;
  } else {
    int i = (blk - xblocks - wblocks) * 256 + tid;
    if (i < dn) denom[i] = 0.f;
  }
}

// qk = xb @ wb^T + bias (bf16 MFMA), double-buffered stage, LDS-staged epilogue.
// Main cols (p<512) -> qkb (row stride RQ); tail cols (512..519) -> tl[N][8].
__global__ void __launch_bounds__(256) gemm_mfma(
    const u16* __restrict__ xb, const u16* __restrict__ wb,
    const float* __restrict__ bias, u16* __restrict__ qkb,
    u16* __restrict__ tl, int M)
{
  __shared__ u16 smem[GBM * EPITCH];   // 38 KB; K-loop uses first 32 KB as 2x(A,B)
  const int tid  = threadIdx.x;
  const int wave = tid >> 6, lane = tid & 63;
  const int l15 = lane & 15, lhi = lane >> 4;
  const int row0 = blockIdx.x * GBM, p0 = blockIdx.y * GBN;
  const int wr = (wave >> 1) * 64, wc = (wave & 1) * 64;

  f32x4 acc[4][4];
  #pragma unroll
  for (int m = 0; m < 4; ++m)
    #pragma unroll
    for (int n = 0; n < 4; ++n) acc[m][n] = (f32x4){0.f, 0.f, 0.f, 0.f};

#define STAGE(b, k0) do {                                                     \
    u16* As_ = smem + (b) * 8192;                                             \
    u16* Bs_ = As_ + 4096;                                                    \
    _Pragma("unroll")                                                         \
    for (int i_ = 0; i_ < 2; ++i_) {                                          \
      int f_ = wave * 128 + i_ * 64 + lane;                                   \
      int r_ = f_ >> 2, c_ = f_ & 3;                                          \
      const u16* gA = xb + (size_t)(row0 + r_) * K_DIM + (k0) + c_ * 8;       \
      __builtin_amdgcn_global_load_lds(                                       \
          (const __attribute__((address_space(1))) void*)gA,                  \
          (__attribute__((address_space(3))) void*)(As_ + (wave*128 + i_*64)*8), \
          16, 0, 0);                                                          \
      const u16* gB = wb + (size_t)(p0 + r_) * K_DIM + (k0) + c_ * 8;         \
      __builtin_amdgcn_global_load_lds(                                       \
          (const __attribute__((address_space(1))) void*)gB,                  \
          (__attribute__((address_space(3))) void*)(Bs_ + (wave*128 + i_*64)*8), \
          16, 0, 0);                                                          \
    }                                                                         \
  } while (0)

  STAGE(0, 0);
  asm volatile("s_waitcnt vmcnt(0)" ::: "memory");
  __syncthreads();

  #pragma unroll
  for (int t = 0; t < K_DIM / GBK; ++t) {
    if (t < K_DIM / GBK - 1) STAGE((t + 1) & 1, (t + 1) * GBK);
    const u16* As = smem + (t & 1) * 8192;
    const u16* Bs = As + 4096;
    short8 af[4], bf[4];
    #pragma unroll
    for (int m = 0; m < 4; ++m)
      af[m] = *(const short8*)(As + (size_t)(wr + m * 16 + l15) * GBK + lhi * 8);
    #pragma unroll
    for (int n = 0; n < 4; ++n)
      bf[n] = *(const short8*)(Bs + (size_t)(wc + n * 16 + l15) * GBK + lhi * 8);
    #pragma unroll
    for (int m = 0; m < 4; ++m)
      #pragma unroll
      for (int n = 0; n < 4; ++n)
        acc[m][n] = __builtin_amdgcn_mfma_f32_16x16x32_bf16(af[m], bf[n], acc[m][n], 0, 0, 0);
    if (t < K_DIM / GBK - 1) {
      asm volatile("s_waitcnt vmcnt(0)" ::: "memory");
      __syncthreads();
    }
  }
#undef STAGE

  __syncthreads();   // all waves done reading K-loop buffers; reuse smem for C

  // acc (+bias) -> LDS bf16 tile [128][EPITCH]
  #pragma unroll
  for (int n = 0; n < 4; ++n) {
    int col = wc + n * 16 + l15;
    float bvv = bias[p0 + col];
    #pragma unroll
    for (int m = 0; m < 4; ++m) {
      #pragma unroll
      for (int r = 0; r < 4; ++r) {
        int row = wr + m * 16 + lhi * 4 + r;
        smem[row * EPITCH + col] = f2b(acc[m][n][r] + bvv);
      }
    }
  }
  __syncthreads();

  // wide stores: each wave handles 32 rows, 4 rows x 16 chunks per iter
  if (p0 < 512) {
    #pragma unroll
    for (int it = 0; it < 8; ++it) {
      int row  = wave * 32 + it * 4 + lhi;
      int grow = row0 + row;
      uint4 v = *(const uint4*)(smem + row * EPITCH + l15 * 8);
      if (grow < M)
        *(uint4*)(qkb + (size_t)grow * RQ + p0 + l15 * 8) = v;
    }
  } else {
    // tails tile: cols 0..7 (= p 512..519) -> tl[row][0..7]
    #pragma unroll
    for (int it = 0; it < 8; ++it) {
      int row  = wave * 32 + it * 4 + lhi;
      int grow = row0 + row;
      if (l15 == 0 && grow < M) {
        uint4 v = *(const uint4*)(smem + row * EPITCH);
        *(uint4*)(tl + (size_t)grow * 8) = v;
      }
    }
  }
}

// 8 edges per wave, 8 lanes per edge; q[src] & k[dst] main blocks 512 B each,
// tails from dense tl[N][8] (L2-resident).
__global__ void __launch_bounds__(256) edge_pass(
    const u16* __restrict__ qkb, const u16* __restrict__ tl,
    const int* __restrict__ ei,
    float* __restrict__ exb, float* __restrict__ denom, int E)
{
  const int tid  = threadIdx.x;
  const int wave = tid >> 6, lane = tid & 63;
  const int g = lane >> 3;          // edge slot in wave
  const int l = lane & 7;           // lane within edge
  const int e = (blockIdx.x * 4 + wave) * 8 + g;
  const bool valid = e < E;
  const int ec = valid ? e : 0;
  const int src = ei[ec];
  const int dst = ei[E + ec];

  const u16* qrow = qkb + ((size_t)src * RQ) + l * 32;
  const u16* krow = qkb + ((size_t)dst * RQ) + 256 + l * 32;

  // tails: lane l==0 loads qt[src] (8 B), l==1 loads kt[dst] (8 B)
  int2 ti = make_int2(0, 0);
  if (l < 2) {
    const u16* tp = tl + (size_t)(l ? dst : src) * 8 + (l ? 4 : 0);
    ti = *(const int2*)tp;
  }

  f32x2 a2 = {0.f, 0.f};
  #pragma unroll
  for (int c = 0; c < 4; ++c) {
    uint4 qv = *(const uint4*)(qrow + c * 8);
    uint4 kv = *(const uint4*)(krow + c * 8);
    const unsigned* qd = (const unsigned*)&qv;
    const unsigned* kd = (const unsigned*)&kv;
    #pragma unroll
    for (int j = 0; j < 4; ++j) {
      f32x2 qa = { asf(qd[j] << 16), asf(qd[j] & 0xffff0000u) };
      f32x2 ka = { asf(kd[j] << 16), asf(kd[j] & 0xffff0000u) };
      a2 += qa * ka;
    }
  }
  float s = a2[0] + a2[1];
  s += __shfl_xor(s, 1);            // head sum (lanes 2h, 2h+1)

  // tail product: even lane gets qt[h] (from lane 8g), odd lane kt[h] (from 8g+1)
  const int h = l >> 1;
  int idxA = ((g << 3) | (l & 1)) << 2;
  int w01 = __builtin_amdgcn_ds_bpermute(idxA, ti.x);
  int w23 = __builtin_amdgcn_ds_bpermute(idxA, ti.y);
  unsigned wsel = (h & 2) ? (unsigned)w23 : (unsigned)w01;
  float tv = (h & 1) ? asf(wsel & 0xffff0000u) : asf(wsel << 16);
  float to = __shfl_xor(tv, 1);
  s = fmaf(tv, to, s);

  float ev = __expf(s);             // |s| <~ 8: fp32-safe, no max-subtraction
  if (valid && (l & 1) == 0) {
    exb[(size_t)e * 4 + h] = ev;
    unsafeAtomicAdd(&denom[(size_t)src * 4 + h], ev);
  }
}

__global__ void __launch_bounds__(256) finalize_k(
    const float* __restrict__ exb, const float* __restrict__ denom,
    const int* __restrict__ ei, float* __restrict__ out, int E)
{
  int e = blockIdx.x * 256 + threadIdx.x;
  if (e >= E) return;
  int src = ei[e];
  float4 ev = *(const float4*)(exb + (size_t)e * 4);
  float4 dv = *(const float4*)(denom + (size_t)src * 4);
  out[e] = 0.25f * (ev.x / dv.x + ev.y / dv.y + ev.z / dv.z + ev.w / dv.w);
}

extern "C" void kernel_launch(void* const* d_in, const int* in_sizes, int n_in,
                              void* d_out, int out_size, void* d_ws, size_t ws_size,
                              hipStream_t stream)
{
  const float* x  = (const float*)d_in[0];
  const int*   ei = (const int*)d_in[1];
  const float* W  = (const float*)d_in[2];
  const float* b  = (const float*)d_in[3];

  const int F = in_sizes[2] / in_sizes[3];   // 256
  const int M = in_sizes[0] / F;             // 50000
  const int E = in_sizes[1] / 2;             // 800000

  const int mblocks = (M + GBM - 1) / GBM;
  const int Mpad    = mblocks * GBM;

  // ws: xb bf16 Mpad*256 | wb bf16 NPAD*256 | qkb bf16 M*RQ | tl bf16 M*8 |
  //     bias f32 NPAD | exb f32 E*4 | denom f32 M*4
  u16* xb  = (u16*)d_ws;
  u16* wb  = xb + (size_t)Mpad * K_DIM;
  u16* qkb = wb + (size_t)NPAD * K_DIM;
  u16* tl  = qkb + (size_t)M * RQ;
  float* bias  = (float*)(tl + (size_t)M * 8);
  float* exb   = bias + NPAD;
  float* denom = exb + (size_t)E * 4;

  const int xblocks = (Mpad * (K_DIM / 8) + 255) / 256;
  const int wblocks = (NPAD * (K_DIM / 8) + 255) / 256;
  const int dn      = M * 4;
  const int zblocks = (dn + 255) / 256;
  hipLaunchKernelGGL(prep, dim3(xblocks + wblocks + zblocks), dim3(256), 0, stream,
                     x, W, b, xb, wb, bias, denom, M, Mpad, xblocks, wblocks, dn);

  dim3 gg(mblocks, NPAD / GBN);
  hipLaunchKernelGGL(gemm_mfma, gg, dim3(256), 0, stream, xb, wb, bias, qkb, tl, M);

  int eblocks = (E + 31) / 32;   // 32 edges per 256-thread block (8 per wave)
  hipLaunchKernelGGL(edge_pass, dim3(eblocks), dim3(256), 0, stream,
                     qkb, tl, ei, exb, denom, E);

  hipLaunchKernelGGL(finalize_k, dim3((E + 255) / 256), dim3(256), 0, stream,
                     exb, denom, ei, (float*)d_out, E);
}